// Round 15
// baseline (295.447 us; speedup 1.0000x reference)
//
#include <hip/hip_runtime.h>
#include <math.h>
#include <stdint.h>

#define DIM_ 1024
#define HEADS_ 16
#define DK_ 64
#define B_ 2
#define L_ 2048
#define BH_ (B_*HEADS_)
#define M_ (B_*L_)

typedef __attribute__((ext_vector_type(4))) float f32x4;
typedef __attribute__((ext_vector_type(8))) short bf16x8;
typedef __attribute__((ext_vector_type(4))) short bf16x4;

#define QSCALE 0.18033688f   // 0.125 * log2(e): softmax in exp2 domain

static __device__ __forceinline__ short f2bf(float f) {
    uint32_t u = __builtin_bit_cast(uint32_t, f);
    u += 0x7fffu + ((u >> 16) & 1u);
    return (short)(u >> 16);
}
static __device__ __forceinline__ void gload16(const void* g, void* l) {
    __builtin_amdgcn_global_load_lds(
        (const __attribute__((address_space(1))) unsigned int*)g,
        (__attribute__((address_space(3))) unsigned int*)l, 16, 0, 0);
}

// ------------------------------------------------------------ prep (fused): fp32->bf16 cvt + W transpose
__global__ __launch_bounds__(256)
void prep(const float* __restrict__ xout, const float* __restrict__ xctx,
          const float* __restrict__ Wq, const float* __restrict__ Wk,
          const float* __restrict__ Wv, const float* __restrict__ Wo,
          short* __restrict__ xoutb, short* __restrict__ xctxb,
          short* __restrict__ WqT, short* __restrict__ WkT,
          short* __restrict__ WvT, short* __restrict__ WoT)
{
    __shared__ float ts[64][65];
    const int bid = blockIdx.x;
    const int tid = threadIdx.x;
    if (bid < 4096) {
        const int id = bid * 256 + tid;
        const int nA = (M_ * DIM_) / 8;
        const float* src = (id < nA) ? xout : xctx;
        short* dst = (id < nA) ? xoutb : xctxb;
        const int c = (id < nA) ? id : id - nA;
        const f32x4 v0 = *(const f32x4*)&src[(size_t)c * 8];
        const f32x4 v1 = *(const f32x4*)&src[(size_t)c * 8 + 4];
        bf16x8 o;
#pragma unroll
        for (int i = 0; i < 4; ++i) { o[i] = f2bf(v0[i]); o[4 + i] = f2bf(v1[i]); }
        *(bf16x8*)&dst[(size_t)c * 8] = o;
        return;
    }
    const int flat = bid - 4096;
    const int z = flat >> 9;
    const int rem = flat & 511;
    const int K = (z == 3) ? 2 * DIM_ : DIM_;
    const int k0 = (rem & 31) * 64;
    if (k0 >= K) return;
    const int n0 = (rem >> 5) * 64;
    const float* W = (z == 0) ? Wq : (z == 1) ? Wk : (z == 2) ? Wv : Wo;
    short* WT = (z == 0) ? WqT : (z == 1) ? WkT : (z == 2) ? WvT : WoT;
    {
        const int k = tid >> 2, noff = (tid & 3) * 16;
#pragma unroll
        for (int i = 0; i < 4; ++i)
            *(f32x4*)&ts[k][noff + i * 4] =
                *(const f32x4*)&W[(size_t)(k0 + k) * DIM_ + n0 + noff + i * 4];
    }
    __syncthreads();
    {
        const int n = tid >> 2, koff = (tid & 3) * 16;
#pragma unroll
        for (int c = 0; c < 2; ++c) {
            bf16x8 o;
#pragma unroll
            for (int i = 0; i < 8; ++i) o[i] = f2bf(ts[koff + c * 8 + i][n]);
            *(bf16x8*)&WT[(size_t)(n0 + n) * K + k0 + koff + c * 8] = o;
        }
    }
}

// ------------------------------------------------------------ QKV GEMM (round-8: MFMA, gload_lds, BK=64, XOR-swizzled LDS)
__global__ __launch_bounds__(256)
void qkv_mfma(const short* __restrict__ xoutb, const short* __restrict__ xctxb,
              const short* __restrict__ WqT, const short* __restrict__ WkT,
              const short* __restrict__ WvT,
              const float* __restrict__ bq, const float* __restrict__ bk,
              const float* __restrict__ bv,
              short* __restrict__ qh, short* __restrict__ kh, short* __restrict__ vT)
{
    const int z = blockIdx.z;
    const short* A  = (z == 0) ? xoutb : xctxb;
    const short* Bt = (z == 0) ? WqT : (z == 1) ? WkT : WvT;
    const float* bias = (z == 0) ? bq : (z == 1) ? bk : bv;

    const int flat = blockIdx.y * 8 + blockIdx.x;
    const int wgs = (flat & 7) * 32 + (flat >> 3);
    const int col0 = (wgs & 7) * 128;
    const int row0 = (wgs >> 3) * 128;
    const int tid = threadIdx.x;
    const int lane = tid & 63;
    const int w = tid >> 6;
    const int wm = (w >> 1) * 64, wn = (w & 1) * 64;
    const int l15 = lane & 15, g = lane >> 4;
    const int sub = lane >> 3, slt = lane & 7;

    __shared__ short As[128 * 64];
    __shared__ short Bs[128 * 64];

    const short* pA[4]; const short* pB[4]; short* ldsA[4]; short* ldsB[4];
#pragma unroll
    for (int i = 0; i < 4; ++i) {
        const int r = w * 32 + i * 8 + sub;
        const int sc = ((slt ^ (r & 7)) * 8);
        pA[i] = A  + (size_t)(row0 + r) * DIM_ + sc;
        pB[i] = Bt + (size_t)(col0 + r) * DIM_ + sc;
        ldsA[i] = &As[(w * 32 + i * 8) * 64];
        ldsB[i] = &Bs[(w * 32 + i * 8) * 64];
    }

    f32x4 acc[4][4];
#pragma unroll
    for (int mi = 0; mi < 4; ++mi)
#pragma unroll
        for (int ni = 0; ni < 4; ++ni) acc[mi][ni] = (f32x4)0.f;

    for (int k0 = 0; k0 < DIM_; k0 += 64) {
#pragma unroll
        for (int i = 0; i < 4; ++i) {
            gload16(pA[i] + k0, ldsA[i]);
            gload16(pB[i] + k0, ldsB[i]);
        }
        __syncthreads();
        bf16x8 af[4][2], bfr[4][2];
#pragma unroll
        for (int mi = 0; mi < 4; ++mi) {
            const int wa = wm + mi * 16 + l15;
#pragma unroll
            for (int ks = 0; ks < 2; ++ks)
                af[mi][ks] = *(const bf16x8*)&As[wa * 64 + (((ks * 4 + g) ^ (wa & 7)) * 8)];
        }
#pragma unroll
        for (int ni = 0; ni < 4; ++ni) {
            const int wb = wn + ni * 16 + l15;
#pragma unroll
            for (int ks = 0; ks < 2; ++ks)
                bfr[ni][ks] = *(const bf16x8*)&Bs[wb * 64 + (((ks * 4 + g) ^ (wb & 7)) * 8)];
        }
        __builtin_amdgcn_s_setprio(1);
#pragma unroll
        for (int mi = 0; mi < 4; ++mi)
#pragma unroll
            for (int ni = 0; ni < 4; ++ni)
#pragma unroll
                for (int ks = 0; ks < 2; ++ks)
                    acc[mi][ni] = __builtin_amdgcn_mfma_f32_16x16x32_bf16(af[mi][ks], bfr[ni][ks], acc[mi][ni], 0, 0, 0);
        __builtin_amdgcn_s_setprio(0);
        __syncthreads();
    }

#pragma unroll
    for (int ni = 0; ni < 4; ++ni) {
        const int col = col0 + wn + ni * 16 + l15;
        const int h = col >> 6, dk = col & 63;
        const float bb = bias[col];
#pragma unroll
        for (int mi = 0; mi < 4; ++mi) {
            const int rowb = row0 + wm + mi * 16 + g * 4;
            const int b = rowb >> 11;
            const int l = rowb & (L_ - 1);
            const int bh = b * 16 + h;
            if (z == 2) {
                bf16x4 o;
#pragma unroll
                for (int r = 0; r < 4; ++r) o[r] = f2bf(acc[mi][ni][r] + bb);
                *(bf16x4*)&vT[(size_t)(bh * 64 + dk) * L_ + l] = o;
            } else {
                short* dst = (z == 0) ? qh : kh;
                const float sc = (z == 0) ? QSCALE : 1.0f;
#pragma unroll
                for (int r = 0; r < 4; ++r)
                    dst[((size_t)bh * L_ + l + r) * DK_ + dk] = f2bf((acc[mi][ni][r] + bb) * sc);
            }
        }
    }
}

// ------------------------------------------------------------ fused attention v12: QBLK=128
// 8 waves, each owns 16 q-rows x full 64-kv width (no wk split): 16 MFMA/wave/iter,
// no stat merge, no epilogue merge. Sum-only softmax (c=0). Round-8 wait schedule.
__global__ __launch_bounds__(512, 8)
void attn_mfma(const short* __restrict__ qh, const short* __restrict__ kh,
               const short* __restrict__ vT,
               float* __restrict__ attn, short* __restrict__ ctxTb)
{
    const int bid = blockIdx.x;
    const int wg = (bid & 7) * 64 + (bid >> 3);       // XCD-contiguous: 4 heads/XCD
    const int bh = wg >> 4;
    const int q0 = (wg & 15) * 128;

    const int tid = threadIdx.x;
    const int lane = tid & 63;
    const int w = tid >> 6;
    const int l15 = lane & 15, g = lane >> 4;

    // arena: pass-1 ring = 4 x 4096 shorts @ 0,4096,8192,12288 (32KB);
    // pass 2: Kb0@0, Kb1@4096, Vb@8192. Psb @16384: 128 rows x 72 shorts (18KB).
    __shared__ short SM[25600];                        // 51.2 KB
    short* const Kb0 = SM;
    short* const Kb1 = SM + 4096;
    short* const Vb  = SM + 8192;
    short* const Psb = SM + 16384;

    const short* kbase = kh + (size_t)bh * (L_ * DK_);
    const short* vbase = vT + (size_t)bh * (DK_ * L_);

    const int lr = lane >> 3, ls = lane & 7;
    const int srow = w * 8 + lr;
    const short* kSrc = kbase + (size_t)srow * DK_ + ((ls ^ (srow & 7)) * 8);
    const short* vSrc = vbase + (size_t)srow * L_ + ((ls ^ (srow & 7)) * 8);

    bf16x8 qf[2];
#pragma unroll
    for (int ks = 0; ks < 2; ++ks)
        qf[ks] = *(const bf16x8*)&qh[((size_t)bh * L_ + q0 + w * 16 + l15) * DK_ + ks * 32 + g * 8];

    int kbOff[4][2], vbOff[4][2];
#pragma unroll
    for (int cc = 0; cc < 4; ++cc)
#pragma unroll
        for (int ks = 0; ks < 2; ++ks) {
            const int row = cc * 16 + l15;
            kbOff[cc][ks] = row * 64 + (((ks * 4 + g) ^ (row & 7)) * 8);
        }
#pragma unroll
    for (int nf = 0; nf < 4; ++nf)
#pragma unroll
        for (int ks = 0; ks < 2; ++ks) {
            const int row = nf * 16 + l15;
            vbOff[nf][ks] = row * 64 + (((ks * 4 + g) ^ (row & 7)) * 8);
        }

    // ---------------- pass 1: SUM-ONLY stats (c=0), 4-deep K ring
    float s[4];
#pragma unroll
    for (int r = 0; r < 4; ++r) s[r] = 0.f;

#pragma unroll
    for (int i = 0; i < 3; ++i)
        gload16(kSrc + (size_t)i * 64 * DK_, SM + (i << 12) + w * 512);
    asm volatile("s_waitcnt vmcnt(2)" ::: "memory");   // K(0) landed
    __builtin_amdgcn_sched_barrier(0);
    __builtin_amdgcn_s_barrier();

    for (int t = 0; t < 32; ++t) {
        if (t < 29)
            gload16(kSrc + (size_t)(t + 3) * 64 * DK_, SM + (((t + 3) & 3) << 12) + w * 512);
        const short* kb = SM + ((t & 3) << 12);
        f32x4 sa[4];
#pragma unroll
        for (int cc = 0; cc < 4; ++cc) sa[cc] = (f32x4)0.f;
        __builtin_amdgcn_s_setprio(1);
#pragma unroll
        for (int cc = 0; cc < 4; ++cc)
#pragma unroll
            for (int ks = 0; ks < 2; ++ks)
                sa[cc] = __builtin_amdgcn_mfma_f32_16x16x32_bf16(qf[ks], *(const bf16x8*)&kb[kbOff[cc][ks]], sa[cc], 0, 0, 0);
        __builtin_amdgcn_s_setprio(0);
#pragma unroll
        for (int r = 0; r < 4; ++r)
            s[r] += (exp2f(sa[0][r]) + exp2f(sa[1][r])) + (exp2f(sa[2][r]) + exp2f(sa[3][r]));
        if (t < 29)       { asm volatile("s_waitcnt vmcnt(2)" ::: "memory"); }
        else if (t == 29) { asm volatile("s_waitcnt vmcnt(1)" ::: "memory"); }
        else if (t == 30) { asm volatile("s_waitcnt vmcnt(0)" ::: "memory"); }
        __builtin_amdgcn_sched_barrier(0);
        if (t < 31) __builtin_amdgcn_s_barrier();
    }
    // cross-lane sum over the 16-lane col groups (kv split across l15)
#pragma unroll
    for (int mask = 1; mask <= 8; mask <<= 1)
#pragma unroll
        for (int r = 0; r < 4; ++r)
            s[r] += __shfl_xor(s[r], mask);
    float li[4];
#pragma unroll
    for (int r = 0; r < 4; ++r) li[r] = -log2f(s[r]);

    // prologue for pass 2 (buf0 free: last pass-1 read of buf0 was t=28; all waves in t=31 now)
    gload16(kSrc, Kb0 + w * 512);                      // K(0)
    f32x4 cacc[4];
#pragma unroll
    for (int nf = 0; nf < 4; ++nf) cacc[nf] = (f32x4)0.f;

    float* attnB = attn + ((size_t)bh * L_ + q0) * L_;

    asm volatile("s_waitcnt vmcnt(0)" ::: "memory");   // K(0) landed
    __builtin_amdgcn_sched_barrier(0);
    __builtin_amdgcn_s_barrier();

    // ---------------- pass 2: per-iter vmem order: V(t), K(t+1), stores(t)x16
    for (int t = 0; t < 32; ++t) {
        if (t) {
            asm volatile("s_waitcnt vmcnt(16)" ::: "memory");  // K(t) landed; 16 stores fly
            __builtin_amdgcn_sched_barrier(0);
            __builtin_amdgcn_s_barrier();
        }
        gload16(vSrc + t * 64, Vb + w * 512);                   // V(t)
        {
            const int tn = (t < 31) ? t + 1 : t;                // uniform issue count
            gload16(kSrc + (size_t)tn * 64 * DK_, ((t & 1) ? Kb0 : Kb1) + w * 512);
        }
        const short* kb = (t & 1) ? Kb1 : Kb0;
        f32x4 sa[4];
#pragma unroll
        for (int cc = 0; cc < 4; ++cc) sa[cc] = (f32x4)0.f;
        __builtin_amdgcn_s_setprio(1);
#pragma unroll
        for (int cc = 0; cc < 4; ++cc)
#pragma unroll
            for (int ks = 0; ks < 2; ++ks)
                sa[cc] = __builtin_amdgcn_mfma_f32_16x16x32_bf16(qf[ks], *(const bf16x8*)&kb[kbOff[cc][ks]], sa[cc], 0, 0, 0);
        __builtin_amdgcn_s_setprio(0);
#pragma unroll
        for (int cc = 0; cc < 4; ++cc)
#pragma unroll
            for (int r = 0; r < 4; ++r) {
                const float p = exp2f(sa[cc][r] + li[r]);       // normalized (c=0 softmax)
                Psb[(w * 16 + g * 4 + r) * 72 + cc * 16 + l15] = f2bf(p);
                __builtin_nontemporal_store(
                    p, attnB + (size_t)(w * 16 + g * 4 + r) * L_ + t * 64 + cc * 16 + l15);
            }
        // V(t) landed (17 newer: K(t+1)+16 stores); own Psb writes done (intra-wave)
        asm volatile("s_waitcnt vmcnt(17) lgkmcnt(0)" ::: "memory");
        __builtin_amdgcn_sched_barrier(0);
        __builtin_amdgcn_s_barrier();
        bf16x8 pa[2];
#pragma unroll
        for (int ks = 0; ks < 2; ++ks)
            pa[ks] = *(const bf16x8*)&Psb[(w * 16 + l15) * 72 + ks * 32 + g * 8];
        __builtin_amdgcn_s_setprio(1);
#pragma unroll
        for (int nf = 0; nf < 4; ++nf)
#pragma unroll
            for (int ks = 0; ks < 2; ++ks)
                cacc[nf] = __builtin_amdgcn_mfma_f32_16x16x32_bf16(pa[ks], *(const bf16x8*)&Vb[vbOff[nf][ks]], cacc[nf], 0, 0, 0);
        __builtin_amdgcn_s_setprio(0);
    }

    // epilogue: direct per-wave ctx^T store (no cross-wave merge)
#pragma unroll
    for (int nf = 0; nf < 4; ++nf) {
        bf16x4 ob;
#pragma unroll
        for (int r = 0; r < 4; ++r) ob[r] = f2bf(cacc[nf][r]);
        *(bf16x4*)&ctxTb[(size_t)(bh * 64 + nf * 16 + l15) * L_ + q0 + w * 16 + g * 4] = ob;
    }
}

// ------------------------------------------------------------ output projection (round-8: MFMA, BM=128 BN=64)
__global__ __launch_bounds__(256)
void out_mfma(const short* __restrict__ ctxTb, const short* __restrict__ xoutb,
              const short* __restrict__ WoT, const float* __restrict__ bo,
              float* __restrict__ out)
{
    const int flat = blockIdx.y * 16 + blockIdx.x;
    const int wgs = (flat & 7) * 64 + (flat >> 3);
    const int col0 = (wgs & 15) * 64;
    const int row0 = (wgs >> 4) * 128;
    const int tid = threadIdx.x;
    const int lane = tid & 63;
    const int w = tid >> 6;
    const int wm = (w >> 1) * 64, wn = (w & 1) * 32;
    const int l15 = lane & 15, g = lane >> 4;
    const int sub = lane >> 3, slt = lane & 7;

    __shared__ short As[128 * 64];
    __shared__ short Bs[64 * 64];

    const short* pA1[4]; const short* pA2[4]; const short* pB[2];
    short* ldsA[4]; short* ldsB[2];
#pragma unroll
    for (int i = 0; i < 4; ++i) {
        const int r = w * 32 + i * 8 + sub;
        const int rr = row0 + r;
        const int b = rr >> 11, l_ = rr & (L_ - 1);
        const int bh = b * 16 + (l_ >> 7), d = (l_ & 127) >> 1;
        const size_t off1 = ((size_t)(bh * 64 + d) << 11) + (size_t)((l_ & 1) << 10);
        const int sc = ((slt ^ (r & 7)) * 8);
        pA1[i] = ctxTb + off1 + sc;
        pA2[i] = xoutb + (size_t)rr * DIM_ + sc;
        ldsA[i] = &As[(w * 32 + i * 8) * 64];
    }
#pragma unroll
    for (int i = 0; i < 2; ++i) {
        const int r = w * 16 + i * 8 + sub;
        const int sc = ((slt ^ (r & 7)) * 8);
        pB[i]  = WoT + (size_t)(col0 + r) * (2 * DIM_) + sc;
        ldsB[i] = &Bs[(w * 16 + i * 8) * 64];
    }

    f32x4 acc[4][2];
#pragma unroll
    for (int mi = 0; mi < 4; ++mi)
#pragma unroll
        for (int ni = 0; ni < 2; ++ni) acc[mi][ni] = (f32x4)0.f;

    for (int k0 = 0; k0 < 2 * DIM_; k0 += 64) {
        const bool first = (k0 < DIM_);
        const int kk = first ? k0 : k0 - DIM_;
#pragma unroll
        for (int i = 0; i < 4; ++i)
            gload16(first ? (pA1[i] + kk) : (pA2[i] + kk), ldsA[i]);
#pragma unroll
        for (int i = 0; i < 2; ++i)
            gload16(pB[i] + k0, ldsB[i]);
        __syncthreads();
        bf16x8 af[4][2], bfr[2][2];
#pragma unroll
        for (int mi = 0; mi < 4; ++mi) {
            const int wa = wm + mi * 16 + l15;
#pragma unroll
            for (int ks = 0; ks < 2; ++ks)
                af[mi][ks] = *(const bf16x8*)&As[wa * 64 + (((ks * 4 + g) ^ (wa & 7)) * 8)];
        }
#pragma unroll
        for (int ni = 0; ni < 2; ++ni) {
            const int wb = wn + ni * 16 + l15;
#pragma unroll
            for (int ks = 0; ks < 2; ++ks)
                bfr[ni][ks] = *(const bf16x8*)&Bs[wb * 64 + (((ks * 4 + g) ^ (wb & 7)) * 8)];
        }
        __builtin_amdgcn_s_setprio(1);
#pragma unroll
        for (int mi = 0; mi < 4; ++mi)
#pragma unroll
            for (int ni = 0; ni < 2; ++ni)
#pragma unroll
                for (int ks = 0; ks < 2; ++ks)
                    acc[mi][ni] = __builtin_amdgcn_mfma_f32_16x16x32_bf16(af[mi][ks], bfr[ni][ks], acc[mi][ni], 0, 0, 0);
        __builtin_amdgcn_s_setprio(0);
        __syncthreads();
    }

#pragma unroll
    for (int ni = 0; ni < 2; ++ni) {
        const int col = col0 + wn + ni * 16 + l15;
        const float bb = bo[col];
#pragma unroll
        for (int mi = 0; mi < 4; ++mi) {
            const int rowb = row0 + wm + mi * 16 + g * 4;
#pragma unroll
            for (int r = 0; r < 4; ++r)
                out[(size_t)(rowb + r) * DIM_ + col] = tanhf(acc[mi][ni][r] + bb);
        }
    }
}

// ------------------------------------------------------------ launch
extern "C" void kernel_launch(void* const* d_in, const int* in_sizes, int n_in,
                              void* d_out, int out_size, void* d_ws, size_t ws_size,
                              hipStream_t stream)
{
    const float* xout = (const float*)d_in[0];
    const float* xctx = (const float*)d_in[1];
    const float* Wq = (const float*)d_in[2];
    const float* bq = (const float*)d_in[3];
    const float* Wk = (const float*)d_in[4];
    const float* bk = (const float*)d_in[5];
    const float* Wv = (const float*)d_in[6];
    const float* bv = (const float*)d_in[7];
    const float* Wo = (const float*)d_in[8];
    const float* bo = (const float*)d_in[9];

    float* out  = (float*)d_out;
    float* attn = out + (size_t)M_ * DIM_;

    short* ws = (short*)d_ws;
    short* xoutb = ws;
    short* xctxb = xoutb + (size_t)M_ * DIM_;
    short* WqT   = xctxb + (size_t)M_ * DIM_;
    short* WkT   = WqT + (size_t)DIM_ * DIM_;
    short* WvT   = WkT + (size_t)DIM_ * DIM_;
    short* WoT   = WvT + (size_t)DIM_ * DIM_;
    short* qh    = WoT + (size_t)2 * DIM_ * DIM_;
    short* kh    = qh + (size_t)BH_ * L_ * DK_;
    short* vT    = kh + (size_t)BH_ * L_ * DK_;
    short* ctxTb = vT + (size_t)BH_ * L_ * DK_;

    prep<<<6144, 256, 0, stream>>>(xout, xctx, Wq, Wk, Wv, Wo,
                                   xoutb, xctxb, WqT, WkT, WvT, WoT);
    qkv_mfma<<<dim3(8, 32, 3), 256, 0, stream>>>(
        xoutb, xctxb, WqT, WkT, WvT, bq, bk, bv, qh, kh, vT);
    attn_mfma<<<512, 512, 0, stream>>>(qh, kh, vT, attn, ctxTb);
    out_mfma<<<dim3(16, 32), 256, 0, stream>>>(ctxTb, xoutb, WoT, bo, out);
}

// Round 16
// 272.223 us; speedup vs baseline: 1.0853x; 1.0853x over previous
//
#include <hip/hip_runtime.h>
#include <math.h>
#include <stdint.h>

#define DIM_ 1024
#define HEADS_ 16
#define DK_ 64
#define B_ 2
#define L_ 2048
#define BH_ (B_*HEADS_)
#define M_ (B_*L_)

typedef __attribute__((ext_vector_type(4))) float f32x4;
typedef __attribute__((ext_vector_type(8))) short bf16x8;
typedef __attribute__((ext_vector_type(4))) short bf16x4;

#define QSCALE 0.18033688f   // 0.125 * log2(e): softmax in exp2 domain

static __device__ __forceinline__ short f2bf(float f) {
    uint32_t u = __builtin_bit_cast(uint32_t, f);
    u += 0x7fffu + ((u >> 16) & 1u);
    return (short)(u >> 16);
}
static __device__ __forceinline__ void gload16(const void* g, void* l) {
    __builtin_amdgcn_global_load_lds(
        (const __attribute__((address_space(1))) unsigned int*)g,
        (__attribute__((address_space(3))) unsigned int*)l, 16, 0, 0);
}

// ------------------------------------------------------------ prep (fused): fp32->bf16 cvt + W transpose
__global__ __launch_bounds__(256)
void prep(const float* __restrict__ xout, const float* __restrict__ xctx,
          const float* __restrict__ Wq, const float* __restrict__ Wk,
          const float* __restrict__ Wv, const float* __restrict__ Wo,
          short* __restrict__ xoutb, short* __restrict__ xctxb,
          short* __restrict__ WqT, short* __restrict__ WkT,
          short* __restrict__ WvT, short* __restrict__ WoT)
{
    __shared__ float ts[64][65];
    const int bid = blockIdx.x;
    const int tid = threadIdx.x;
    if (bid < 4096) {
        const int id = bid * 256 + tid;
        const int nA = (M_ * DIM_) / 8;
        const float* src = (id < nA) ? xout : xctx;
        short* dst = (id < nA) ? xoutb : xctxb;
        const int c = (id < nA) ? id : id - nA;
        const f32x4 v0 = *(const f32x4*)&src[(size_t)c * 8];
        const f32x4 v1 = *(const f32x4*)&src[(size_t)c * 8 + 4];
        bf16x8 o;
#pragma unroll
        for (int i = 0; i < 4; ++i) { o[i] = f2bf(v0[i]); o[4 + i] = f2bf(v1[i]); }
        *(bf16x8*)&dst[(size_t)c * 8] = o;
        return;
    }
    const int flat = bid - 4096;
    const int z = flat >> 9;
    const int rem = flat & 511;
    const int K = (z == 3) ? 2 * DIM_ : DIM_;
    const int k0 = (rem & 31) * 64;
    if (k0 >= K) return;
    const int n0 = (rem >> 5) * 64;
    const float* W = (z == 0) ? Wq : (z == 1) ? Wk : (z == 2) ? Wv : Wo;
    short* WT = (z == 0) ? WqT : (z == 1) ? WkT : (z == 2) ? WvT : WoT;
    {
        const int k = tid >> 2, noff = (tid & 3) * 16;
#pragma unroll
        for (int i = 0; i < 4; ++i)
            *(f32x4*)&ts[k][noff + i * 4] =
                *(const f32x4*)&W[(size_t)(k0 + k) * DIM_ + n0 + noff + i * 4];
    }
    __syncthreads();
    {
        const int n = tid >> 2, koff = (tid & 3) * 16;
#pragma unroll
        for (int c = 0; c < 2; ++c) {
            bf16x8 o;
#pragma unroll
            for (int i = 0; i < 8; ++i) o[i] = f2bf(ts[koff + c * 8 + i][n]);
            *(bf16x8*)&WT[(size_t)(n0 + n) * K + k0 + koff + c * 8] = o;
        }
    }
}

// ------------------------------------------------------------ QKV GEMM (round-8: MFMA, gload_lds, BK=64, XOR-swizzled LDS)
__global__ __launch_bounds__(256)
void qkv_mfma(const short* __restrict__ xoutb, const short* __restrict__ xctxb,
              const short* __restrict__ WqT, const short* __restrict__ WkT,
              const short* __restrict__ WvT,
              const float* __restrict__ bq, const float* __restrict__ bk,
              const float* __restrict__ bv,
              short* __restrict__ qh, short* __restrict__ kh, short* __restrict__ vT)
{
    const int z = blockIdx.z;
    const short* A  = (z == 0) ? xoutb : xctxb;
    const short* Bt = (z == 0) ? WqT : (z == 1) ? WkT : WvT;
    const float* bias = (z == 0) ? bq : (z == 1) ? bk : bv;

    const int flat = blockIdx.y * 8 + blockIdx.x;
    const int wgs = (flat & 7) * 32 + (flat >> 3);
    const int col0 = (wgs & 7) * 128;
    const int row0 = (wgs >> 3) * 128;
    const int tid = threadIdx.x;
    const int lane = tid & 63;
    const int w = tid >> 6;
    const int wm = (w >> 1) * 64, wn = (w & 1) * 64;
    const int l15 = lane & 15, g = lane >> 4;
    const int sub = lane >> 3, slt = lane & 7;

    __shared__ short As[128 * 64];
    __shared__ short Bs[128 * 64];

    const short* pA[4]; const short* pB[4]; short* ldsA[4]; short* ldsB[4];
#pragma unroll
    for (int i = 0; i < 4; ++i) {
        const int r = w * 32 + i * 8 + sub;
        const int sc = ((slt ^ (r & 7)) * 8);
        pA[i] = A  + (size_t)(row0 + r) * DIM_ + sc;
        pB[i] = Bt + (size_t)(col0 + r) * DIM_ + sc;
        ldsA[i] = &As[(w * 32 + i * 8) * 64];
        ldsB[i] = &Bs[(w * 32 + i * 8) * 64];
    }

    f32x4 acc[4][4];
#pragma unroll
    for (int mi = 0; mi < 4; ++mi)
#pragma unroll
        for (int ni = 0; ni < 4; ++ni) acc[mi][ni] = (f32x4)0.f;

    for (int k0 = 0; k0 < DIM_; k0 += 64) {
#pragma unroll
        for (int i = 0; i < 4; ++i) {
            gload16(pA[i] + k0, ldsA[i]);
            gload16(pB[i] + k0, ldsB[i]);
        }
        __syncthreads();
        bf16x8 af[4][2], bfr[4][2];
#pragma unroll
        for (int mi = 0; mi < 4; ++mi) {
            const int wa = wm + mi * 16 + l15;
#pragma unroll
            for (int ks = 0; ks < 2; ++ks)
                af[mi][ks] = *(const bf16x8*)&As[wa * 64 + (((ks * 4 + g) ^ (wa & 7)) * 8)];
        }
#pragma unroll
        for (int ni = 0; ni < 4; ++ni) {
            const int wb = wn + ni * 16 + l15;
#pragma unroll
            for (int ks = 0; ks < 2; ++ks)
                bfr[ni][ks] = *(const bf16x8*)&Bs[wb * 64 + (((ks * 4 + g) ^ (wb & 7)) * 8)];
        }
        __builtin_amdgcn_s_setprio(1);
#pragma unroll
        for (int mi = 0; mi < 4; ++mi)
#pragma unroll
            for (int ni = 0; ni < 4; ++ni)
#pragma unroll
                for (int ks = 0; ks < 2; ++ks)
                    acc[mi][ni] = __builtin_amdgcn_mfma_f32_16x16x32_bf16(af[mi][ks], bfr[ni][ks], acc[mi][ni], 0, 0, 0);
        __builtin_amdgcn_s_setprio(0);
        __syncthreads();
    }

#pragma unroll
    for (int ni = 0; ni < 4; ++ni) {
        const int col = col0 + wn + ni * 16 + l15;
        const int h = col >> 6, dk = col & 63;
        const float bb = bias[col];
#pragma unroll
        for (int mi = 0; mi < 4; ++mi) {
            const int rowb = row0 + wm + mi * 16 + g * 4;
            const int b = rowb >> 11;
            const int l = rowb & (L_ - 1);
            const int bh = b * 16 + h;
            if (z == 2) {
                bf16x4 o;
#pragma unroll
                for (int r = 0; r < 4; ++r) o[r] = f2bf(acc[mi][ni][r] + bb);
                *(bf16x4*)&vT[(size_t)(bh * 64 + dk) * L_ + l] = o;
            } else {
                short* dst = (z == 0) ? qh : kh;
                const float sc = (z == 0) ? QSCALE : 1.0f;
#pragma unroll
                for (int r = 0; r < 4; ++r)
                    dst[((size_t)bh * L_ + l + r) * DK_ + dk] = f2bf((acc[mi][ni][r] + bb) * sc);
            }
        }
    }
}

// ------------------------------------------------------------ fused attention (round-14 best: sum-only softmax, round-8 schedule)
__global__ __launch_bounds__(512, 8)
void attn_mfma(const short* __restrict__ qh, const short* __restrict__ kh,
               const short* __restrict__ vT,
               float* __restrict__ attn, short* __restrict__ ctxTb)
{
    const int bid = blockIdx.x;
    const int wg = (bid & 7) * 128 + (bid >> 3);      // XCD-contiguous
    const int bh = wg >> 5;
    const int q0 = (wg & 31) * 64;

    const int tid = threadIdx.x;
    const int lane = tid & 63;
    const int w = tid >> 6;
    const int wq = w >> 1, wk = w & 1;
    const int l15 = lane & 15, g = lane >> 4;

    __shared__ short SM[17408];
    short* const Kb0 = SM;
    short* const Kb1 = SM + 4096;
    short* const Vb  = SM + 8192;
    short* const Psb = SM + 12288;                    // 64 x 72
    float* const stat = (float*)(SM + 16896);         // [4][2][16] row-sums

    const short* kbase = kh + (size_t)bh * (L_ * DK_);
    const short* vbase = vT + (size_t)bh * (DK_ * L_);

    const int lr = lane >> 3, ls = lane & 7;
    const int srow = w * 8 + lr;
    const short* kSrc = kbase + (size_t)srow * DK_ + ((ls ^ (srow & 7)) * 8);
    const short* vSrc = vbase + (size_t)srow * L_ + ((ls ^ (srow & 7)) * 8);

    bf16x8 qf[2];
#pragma unroll
    for (int ks = 0; ks < 2; ++ks)
        qf[ks] = *(const bf16x8*)&qh[((size_t)bh * L_ + q0 + wq * 16 + l15) * DK_ + ks * 32 + g * 8];

    int kbOff[2][2], vbOff[4];
#pragma unroll
    for (int cc = 0; cc < 2; ++cc)
#pragma unroll
        for (int ks = 0; ks < 2; ++ks) {
            const int row = wk * 32 + cc * 16 + l15;
            kbOff[cc][ks] = row * 64 + (((ks * 4 + g) ^ (row & 7)) * 8);
        }
#pragma unroll
    for (int nf = 0; nf < 4; ++nf) {
        const int row = nf * 16 + l15;
        vbOff[nf] = row * 64 + (((wk * 4 + g) ^ (row & 7)) * 8);
    }

    // ---------------- pass 1: SUM-ONLY stats (c=0), 4-deep K pipeline
    float s[4];
#pragma unroll
    for (int r = 0; r < 4; ++r) s[r] = 0.f;

#pragma unroll
    for (int i = 0; i < 3; ++i)
        gload16(kSrc + (size_t)i * 64 * DK_, SM + (i << 12) + w * 512);
    asm volatile("s_waitcnt vmcnt(2)" ::: "memory");   // K(0) landed
    __builtin_amdgcn_sched_barrier(0);
    __builtin_amdgcn_s_barrier();

    for (int t = 0; t < 32; ++t) {
        if (t < 29)
            gload16(kSrc + (size_t)(t + 3) * 64 * DK_, SM + (((t + 3) & 3) << 12) + w * 512);
        const short* kb = SM + ((t & 3) << 12);
        f32x4 sa[2];
#pragma unroll
        for (int cc = 0; cc < 2; ++cc) sa[cc] = (f32x4)0.f;
        __builtin_amdgcn_s_setprio(1);
#pragma unroll
        for (int cc = 0; cc < 2; ++cc)
#pragma unroll
            for (int ks = 0; ks < 2; ++ks)
                sa[cc] = __builtin_amdgcn_mfma_f32_16x16x32_bf16(qf[ks], *(const bf16x8*)&kb[kbOff[cc][ks]], sa[cc], 0, 0, 0);
        __builtin_amdgcn_s_setprio(0);
#pragma unroll
        for (int r = 0; r < 4; ++r)
            s[r] += exp2f(sa[0][r]) + exp2f(sa[1][r]);
        if (t < 29)       { asm volatile("s_waitcnt vmcnt(2)" ::: "memory"); }
        else if (t == 29) { asm volatile("s_waitcnt vmcnt(1)" ::: "memory"); }
        else if (t == 30) { asm volatile("s_waitcnt vmcnt(0)" ::: "memory"); }
        __builtin_amdgcn_sched_barrier(0);
        if (t < 31) __builtin_amdgcn_s_barrier();
    }
    // cross-lane sum over the 16-lane col groups
#pragma unroll
    for (int mask = 1; mask <= 8; mask <<= 1)
#pragma unroll
        for (int r = 0; r < 4; ++r)
            s[r] += __shfl_xor(s[r], mask);
    if (l15 == 0) {
#pragma unroll
        for (int r = 0; r < 4; ++r)
            stat[(wq * 2 + wk) * 16 + g * 4 + r] = s[r];
    }
    gload16(kSrc, SM + w * 512);                       // K(0) for pass 2 -> Kb0
    asm volatile("s_waitcnt lgkmcnt(0)" ::: "memory"); // stat visible
    __builtin_amdgcn_s_barrier();
    float li[4];                                       // -log2(row sum)
#pragma unroll
    for (int r = 0; r < 4; ++r) {
        const float st = stat[(wq * 2 + 0) * 16 + g * 4 + r]
                       + stat[(wq * 2 + 1) * 16 + g * 4 + r];
        li[r] = -log2f(st);
    }

    f32x4 cacc[4];
#pragma unroll
    for (int nf = 0; nf < 4; ++nf) cacc[nf] = (f32x4)0.f;

    float* attnB = attn + ((size_t)bh * L_ + q0) * L_;

    asm volatile("s_waitcnt vmcnt(0)" ::: "memory");   // K(0) landed
    __builtin_amdgcn_sched_barrier(0);
    __builtin_amdgcn_s_barrier();

    // ---------------- pass 2: recompute, fp32 register attn stores, PV
    // per-iter vmem issue order: V(t), K(t+1), stores(t)x8
    for (int t = 0; t < 32; ++t) {
        if (t) {
            asm volatile("s_waitcnt vmcnt(8)" ::: "memory");   // K(t) landed; stores keep flying
            __builtin_amdgcn_sched_barrier(0);
            __builtin_amdgcn_s_barrier();
        }
        gload16(vSrc + t * 64, Vb + w * 512);                   // V(t)
        {
            const int tn = (t < 31) ? t + 1 : t;                // uniform issue count
            gload16(kSrc + (size_t)tn * 64 * DK_, ((t & 1) ? Kb0 : Kb1) + w * 512);
        }
        const short* kb = (t & 1) ? Kb1 : Kb0;
        f32x4 sa[2];
#pragma unroll
        for (int cc = 0; cc < 2; ++cc) sa[cc] = (f32x4)0.f;
        __builtin_amdgcn_s_setprio(1);
#pragma unroll
        for (int cc = 0; cc < 2; ++cc)
#pragma unroll
            for (int ks = 0; ks < 2; ++ks)
                sa[cc] = __builtin_amdgcn_mfma_f32_16x16x32_bf16(qf[ks], *(const bf16x8*)&kb[kbOff[cc][ks]], sa[cc], 0, 0, 0);
        __builtin_amdgcn_s_setprio(0);
#pragma unroll
        for (int cc = 0; cc < 2; ++cc)
#pragma unroll
            for (int r = 0; r < 4; ++r) {
                const float p = exp2f(sa[cc][r] + li[r]);       // normalized (c=0 softmax)
                Psb[(wq * 16 + g * 4 + r) * 72 + wk * 32 + cc * 16 + l15] = f2bf(p);
                __builtin_nontemporal_store(
                    p, attnB + (size_t)(wq * 16 + g * 4 + r) * L_ + t * 64 + wk * 32 + cc * 16 + l15);
            }
        // V(t) landed (9 newer: K(t+1)+8 stores), Psb visible
        asm volatile("s_waitcnt vmcnt(9) lgkmcnt(0)" ::: "memory");
        __builtin_amdgcn_sched_barrier(0);
        __builtin_amdgcn_s_barrier();
        const bf16x8 pa = *(const bf16x8*)&Psb[(wq * 16 + l15) * 72 + wk * 32 + g * 8];
        __builtin_amdgcn_s_setprio(1);
#pragma unroll
        for (int nf = 0; nf < 4; ++nf)
            cacc[nf] = __builtin_amdgcn_mfma_f32_16x16x32_bf16(pa, *(const bf16x8*)&Vb[vbOff[nf]], cacc[nf], 0, 0, 0);
        __builtin_amdgcn_s_setprio(0);
    }

    // epilogue: combine kv-halves, store ctx^T bf16
    __syncthreads();
    float* scr = (float*)Kb0;
    float* scr1 = (float*)Kb1;
    if (wk) {
#pragma unroll
        for (int nf = 0; nf < 4; ++nf) {
            float* p = (nf < 2) ? scr : scr1;
            *(f32x4*)&p[(((wq * 2) + (nf & 1)) * 64 + lane) * 4] = cacc[nf];
        }
    }
    __syncthreads();
    if (!wk) {
#pragma unroll
        for (int nf = 0; nf < 4; ++nf) {
            const float* p = (nf < 2) ? scr : scr1;
            const f32x4 o = cacc[nf] + *(const f32x4*)&p[(((wq * 2) + (nf & 1)) * 64 + lane) * 4];
            bf16x4 ob;
#pragma unroll
            for (int r = 0; r < 4; ++r) ob[r] = f2bf(o[r]);
            *(bf16x4*)&ctxTb[(size_t)(bh * 64 + nf * 16 + l15) * L_ + q0 + wq * 16 + g * 4] = ob;
        }
    }
}

// ------------------------------------------------------------ output projection (round-8: MFMA, BM=128 BN=64)
__global__ __launch_bounds__(256)
void out_mfma(const short* __restrict__ ctxTb, const short* __restrict__ xoutb,
              const short* __restrict__ WoT, const float* __restrict__ bo,
              float* __restrict__ out)
{
    const int flat = blockIdx.y * 16 + blockIdx.x;
    const int wgs = (flat & 7) * 64 + (flat >> 3);
    const int col0 = (wgs & 15) * 64;
    const int row0 = (wgs >> 4) * 128;
    const int tid = threadIdx.x;
    const int lane = tid & 63;
    const int w = tid >> 6;
    const int wm = (w >> 1) * 64, wn = (w & 1) * 32;
    const int l15 = lane & 15, g = lane >> 4;
    const int sub = lane >> 3, slt = lane & 7;

    __shared__ short As[128 * 64];
    __shared__ short Bs[64 * 64];

    const short* pA1[4]; const short* pA2[4]; const short* pB[2];
    short* ldsA[4]; short* ldsB[2];
#pragma unroll
    for (int i = 0; i < 4; ++i) {
        const int r = w * 32 + i * 8 + sub;
        const int rr = row0 + r;
        const int b = rr >> 11, l_ = rr & (L_ - 1);
        const int bh = b * 16 + (l_ >> 7), d = (l_ & 127) >> 1;
        const size_t off1 = ((size_t)(bh * 64 + d) << 11) + (size_t)((l_ & 1) << 10);
        const int sc = ((slt ^ (r & 7)) * 8);
        pA1[i] = ctxTb + off1 + sc;
        pA2[i] = xoutb + (size_t)rr * DIM_ + sc;
        ldsA[i] = &As[(w * 32 + i * 8) * 64];
    }
#pragma unroll
    for (int i = 0; i < 2; ++i) {
        const int r = w * 16 + i * 8 + sub;
        const int sc = ((slt ^ (r & 7)) * 8);
        pB[i]  = WoT + (size_t)(col0 + r) * (2 * DIM_) + sc;
        ldsB[i] = &Bs[(w * 16 + i * 8) * 64];
    }

    f32x4 acc[4][2];
#pragma unroll
    for (int mi = 0; mi < 4; ++mi)
#pragma unroll
        for (int ni = 0; ni < 2; ++ni) acc[mi][ni] = (f32x4)0.f;

    for (int k0 = 0; k0 < 2 * DIM_; k0 += 64) {
        const bool first = (k0 < DIM_);
        const int kk = first ? k0 : k0 - DIM_;
#pragma unroll
        for (int i = 0; i < 4; ++i)
            gload16(first ? (pA1[i] + kk) : (pA2[i] + kk), ldsA[i]);
#pragma unroll
        for (int i = 0; i < 2; ++i)
            gload16(pB[i] + k0, ldsB[i]);
        __syncthreads();
        bf16x8 af[4][2], bfr[2][2];
#pragma unroll
        for (int mi = 0; mi < 4; ++mi) {
            const int wa = wm + mi * 16 + l15;
#pragma unroll
            for (int ks = 0; ks < 2; ++ks)
                af[mi][ks] = *(const bf16x8*)&As[wa * 64 + (((ks * 4 + g) ^ (wa & 7)) * 8)];
        }
#pragma unroll
        for (int ni = 0; ni < 2; ++ni) {
            const int wb = wn + ni * 16 + l15;
#pragma unroll
            for (int ks = 0; ks < 2; ++ks)
                bfr[ni][ks] = *(const bf16x8*)&Bs[wb * 64 + (((ks * 4 + g) ^ (wb & 7)) * 8)];
        }
        __builtin_amdgcn_s_setprio(1);
#pragma unroll
        for (int mi = 0; mi < 4; ++mi)
#pragma unroll
            for (int ni = 0; ni < 2; ++ni)
#pragma unroll
                for (int ks = 0; ks < 2; ++ks)
                    acc[mi][ni] = __builtin_amdgcn_mfma_f32_16x16x32_bf16(af[mi][ks], bfr[ni][ks], acc[mi][ni], 0, 0, 0);
        __builtin_amdgcn_s_setprio(0);
        __syncthreads();
    }

#pragma unroll
    for (int ni = 0; ni < 2; ++ni) {
        const int col = col0 + wn + ni * 16 + l15;
        const float bb = bo[col];
#pragma unroll
        for (int mi = 0; mi < 4; ++mi) {
            const int rowb = row0 + wm + mi * 16 + g * 4;
#pragma unroll
            for (int r = 0; r < 4; ++r)
                out[(size_t)(rowb + r) * DIM_ + col] = tanhf(acc[mi][ni][r] + bb);
        }
    }
}

// ------------------------------------------------------------ launch
extern "C" void kernel_launch(void* const* d_in, const int* in_sizes, int n_in,
                              void* d_out, int out_size, void* d_ws, size_t ws_size,
                              hipStream_t stream)
{
    const float* xout = (const float*)d_in[0];
    const float* xctx = (const float*)d_in[1];
    const float* Wq = (const float*)d_in[2];
    const float* bq = (const float*)d_in[3];
    const float* Wk = (const float*)d_in[4];
    const float* bk = (const float*)d_in[5];
    const float* Wv = (const float*)d_in[6];
    const float* bv = (const float*)d_in[7];
    const float* Wo = (const float*)d_in[8];
    const float* bo = (const float*)d_in[9];

    float* out  = (float*)d_out;
    float* attn = out + (size_t)M_ * DIM_;

    short* ws = (short*)d_ws;
    short* xoutb = ws;
    short* xctxb = xoutb + (size_t)M_ * DIM_;
    short* WqT   = xctxb + (size_t)M_ * DIM_;
    short* WkT   = WqT + (size_t)DIM_ * DIM_;
    short* WvT   = WkT + (size_t)DIM_ * DIM_;
    short* WoT   = WvT + (size_t)DIM_ * DIM_;
    short* qh    = WoT + (size_t)2 * DIM_ * DIM_;
    short* kh    = qh + (size_t)BH_ * L_ * DK_;
    short* vT    = kh + (size_t)BH_ * L_ * DK_;
    short* ctxTb = vT + (size_t)BH_ * L_ * DK_;

    prep<<<6144, 256, 0, stream>>>(xout, xctx, Wq, Wk, Wv, Wo,
                                   xoutb, xctxb, WqT, WkT, WvT, WoT);
    qkv_mfma<<<dim3(8, 32, 3), 256, 0, stream>>>(
        xoutb, xctxb, WqT, WkT, WvT, bq, bk, bv, qh, kh, vT);
    attn_mfma<<<1024, 512, 0, stream>>>(qh, kh, vT, attn, ctxTb);
    out_mfma<<<dim3(16, 32), 256, 0, stream>>>(ctxTb, xoutb, WoT, bo, out);
}